// Round 1
// baseline (36.038 us; speedup 1.0000x reference)
//
#include <hip/hip_runtime.h>

// Problem constants (match reference setup_inputs)
#define BATCH   32
#define NA      3
#define GRID    64
#define NCLS    80
#define MAXB    50
#define NANCH   (NA * GRID * GRID)      // 12288 anchors per image
#define BLK     256
#define BLKS_PER_IMG (NANCH / BLK)      // 48
#define ROWLEN  (NCLS + 5)              // 85 floats per prediction row

// Kernel 1: per-anchor IoU matching + BCE for positive anchors.
// One thread per anchor; deterministic block partials (no atomics).
__global__ __launch_bounds__(BLK) void yolo_match_bce(
    const float* __restrict__ pred,      // (B, NANCH, 85)
    const float* __restrict__ ann,       // (B, MAXB, 5)
    const float* __restrict__ anchors,   // (NANCH, 4)
    float* __restrict__ psum,            // (B, BLKS_PER_IMG)
    int*   __restrict__ pcnt)            // (B, BLKS_PER_IMG)
{
    const int blk = blockIdx.x;                 // 0..47
    const int b   = blockIdx.y;                 // image
    const int n   = blk * BLK + threadIdx.x;    // anchor index

    __shared__ float s_ann[MAXB * 5];
    for (int i = threadIdx.x; i < MAXB * 5; i += BLK)
        s_ann[i] = ann[(size_t)b * MAXB * 5 + i];
    __syncthreads();

    // Anchor box (16B-aligned: n*4 floats)
    const float4 a4 = *reinterpret_cast<const float4*>(anchors + (size_t)n * 4);
    const float ax1 = a4.x - a4.z * 0.5f, ay1 = a4.y - a4.w * 0.5f;
    const float ax2 = a4.x + a4.z * 0.5f, ay2 = a4.y + a4.w * 0.5f;
    const float area_a = (ax2 - ax1) * (ay2 - ay1);

    float best = -1e30f;
    int   bestm = 0;
    #pragma unroll 5
    for (int m = 0; m < MAXB; ++m) {
        const float bcx = s_ann[m * 5 + 0], bcy = s_ann[m * 5 + 1];
        const float bw  = s_ann[m * 5 + 2], bh  = s_ann[m * 5 + 3];
        const float bcl = s_ann[m * 5 + 4];
        const float bx1 = bcx - bw * 0.5f, by1 = bcy - bh * 0.5f;
        const float bx2 = bcx + bw * 0.5f, by2 = bcy + bh * 0.5f;
        float iw = fminf(ax2, bx2) - fmaxf(ax1, bx1); iw = fmaxf(iw, 0.0f);
        float ih = fminf(ay2, by2) - fmaxf(ay1, by1); ih = fmaxf(ih, 0.0f);
        const float inter  = iw * ih;
        const float area_b = (bx2 - bx1) * (by2 - by1);
        const float ua     = fmaxf(area_a + area_b - inter, 1e-8f);
        float iou = inter / ua;
        if (bcl == -1.0f) iou = -1.0f;       // invalid annotation never matches
        if (iou > best) { best = iou; bestm = m; }  // strict > = first-occurrence argmax
    }

    const bool positive = (best >= 0.5f);
    float local = 0.0f;
    if (positive) {
        const float clsv = s_ann[bestm * 5 + 4];
        int ac = (int)fminf(fmaxf(clsv, 0.0f), (float)(NCLS - 1));
        const float* prow = pred + ((size_t)b * NANCH + n) * ROWLEN + 5;
        // BCE over one-hot target: -log(p[ac]) - sum_{c!=ac} log(1-p[c])
        //                        = -log(p[ac]) + log(1-p[ac]) - S,  S = sum_c log(1-p[c])
        float S = 0.0f;
        #pragma unroll
        for (int c = 0; c < NCLS; ++c)
            S += logf(1.0f - prow[c]);
        const float pa = prow[ac];
        local = -logf(pa) + logf(1.0f - pa) - S;
    }

    // Block reduction (deterministic): wave shuffle then cross-wave via LDS
    float v = local;
    int   c = positive ? 1 : 0;
    #pragma unroll
    for (int off = 32; off > 0; off >>= 1) {
        v += __shfl_down(v, off, 64);
        c += __shfl_down(c, off, 64);
    }
    __shared__ float s_sum[BLK / 64];
    __shared__ int   s_cnt[BLK / 64];
    const int wave = threadIdx.x >> 6;
    if ((threadIdx.x & 63) == 0) { s_sum[wave] = v; s_cnt[wave] = c; }
    __syncthreads();
    if (threadIdx.x == 0) {
        float t = 0.0f; int tc = 0;
        #pragma unroll
        for (int w = 0; w < BLK / 64; ++w) { t += s_sum[w]; tc += s_cnt[w]; }
        psum[b * BLKS_PER_IMG + blk] = t;
        pcnt[b * BLKS_PER_IMG + blk] = tc;
    }
}

// Kernel 2: reduce 48 partials per image -> final losses; write all outputs.
__global__ __launch_bounds__(64) void yolo_finalize(
    const float* __restrict__ psum,
    const int*   __restrict__ pcnt,
    float* __restrict__ out)             // (2, B): [cls_losses; reg_losses=0]
{
    const int b = blockIdx.x;
    const int t = threadIdx.x;           // 64 threads
    float v = (t < BLKS_PER_IMG) ? psum[b * BLKS_PER_IMG + t] : 0.0f;
    int   c = (t < BLKS_PER_IMG) ? pcnt[b * BLKS_PER_IMG + t] : 0;
    #pragma unroll
    for (int off = 32; off > 0; off >>= 1) {
        v += __shfl_down(v, off, 64);
        c += __shfl_down(c, off, 64);
    }
    if (t == 0) {
        const int np = (c > 1) ? c : 1;
        out[b]         = v / (float)np;  // cls_loss
        out[BATCH + b] = 0.0f;           // reg_loss (no-op branch in source)
    }
}

extern "C" void kernel_launch(void* const* d_in, const int* in_sizes, int n_in,
                              void* d_out, int out_size, void* d_ws, size_t ws_size,
                              hipStream_t stream) {
    const float* pred    = (const float*)d_in[0];   // (B, A, G, G, 85)
    const float* ann     = (const float*)d_in[1];   // (B, MAXB, 5)
    const float* anchors = (const float*)d_in[2];   // (A, G, G, 4)
    float* out = (float*)d_out;

    float* psum = (float*)d_ws;
    int*   pcnt = (int*)((char*)d_ws + sizeof(float) * BATCH * BLKS_PER_IMG);

    dim3 grid1(BLKS_PER_IMG, BATCH);
    yolo_match_bce<<<grid1, BLK, 0, stream>>>(pred, ann, anchors, psum, pcnt);
    yolo_finalize<<<BATCH, 64, 0, stream>>>(psum, pcnt, out);
}

// Round 2
// 29.479 us; speedup vs baseline: 1.2225x; 1.2225x over previous
//
#include <hip/hip_runtime.h>

// Problem constants (match reference setup_inputs)
#define BATCH   32
#define NA      3
#define GRID    64
#define NCLS    80
#define MAXB    50
#define NANCH   (NA * GRID * GRID)      // 12288 anchors per image
#define BLK     256
#define BLKS_PER_IMG (NANCH / BLK)      // 48
#define ROWLEN  (NCLS + 5)              // 85 floats per prediction row

// Kernel 1: per-anchor IoU matching + BCE for positive anchors.
// Division-free: track best as a fraction (bi/bu) and compare by
// cross-multiplication (all unions > 0). One thread per anchor.
__global__ __launch_bounds__(BLK) void yolo_match_bce(
    const float* __restrict__ pred,      // (B, NANCH, 85)
    const float* __restrict__ ann,       // (B, MAXB, 5)
    const float* __restrict__ anchors,   // (NANCH, 4)
    float* __restrict__ psum,            // (B, BLKS_PER_IMG)
    int*   __restrict__ pcnt)            // (B, BLKS_PER_IMG)
{
    const int blk = blockIdx.x;                 // 0..47
    const int b   = blockIdx.y;                 // image
    const int n   = blk * BLK + threadIdx.x;    // anchor index

    // Precomputed annotation tiles: corners + (area, cls).
    // Invalid anns (cls == -1) get area = 1e30:
    //  - they can never satisfy 2*inter >= union  (union ~1e30)  -> never positive
    //  - they can only become "best" while best_inter == 0, in which case the
    //    class is never consumed (positive is false). Any valid ann with
    //    inter > 0 then immediately beats them (inter*1e30 > bi*ua).
    __shared__ float4 s_box[MAXB];   // x1,y1,x2,y2
    __shared__ float2 s_meta[MAXB];  // area (or 1e30), cls
    if (threadIdx.x < MAXB) {
        const float* a = ann + ((size_t)b * MAXB + threadIdx.x) * 5;
        const float cx = a[0], cy = a[1], w = a[2], h = a[3], cl = a[4];
        const float x1 = cx - w * 0.5f, y1 = cy - h * 0.5f;
        const float x2 = cx + w * 0.5f, y2 = cy + h * 0.5f;
        float area = (x2 - x1) * (y2 - y1);
        if (cl == -1.0f) area = 1e30f;
        s_box[threadIdx.x]  = make_float4(x1, y1, x2, y2);
        s_meta[threadIdx.x] = make_float2(area, cl);
    }
    __syncthreads();

    // Anchor box (16B-aligned: n*4 floats)
    const float4 a4 = *reinterpret_cast<const float4*>(anchors + (size_t)n * 4);
    const float ax1 = a4.x - a4.z * 0.5f, ay1 = a4.y - a4.w * 0.5f;
    const float ax2 = a4.x + a4.z * 0.5f, ay2 = a4.y + a4.w * 0.5f;
    const float area_a = (ax2 - ax1) * (ay2 - ay1);

    float bi = 0.0f, bu = 1.0f;   // best IoU fraction = bi/bu (init 0)
    int   bestm = 0;
    #pragma unroll 10
    for (int m = 0; m < MAXB; ++m) {
        const float4 bb = s_box[m];
        const float2 mm = s_meta[m];
        float iw = fminf(ax2, bb.z) - fmaxf(ax1, bb.x); iw = fmaxf(iw, 0.0f);
        float ih = fminf(ay2, bb.w) - fmaxf(ay1, bb.y); ih = fmaxf(ih, 0.0f);
        const float inter = iw * ih;
        const float ua = fmaxf(area_a + mm.x - inter, 1e-8f);
        // strict > keeps first occurrence, matching jnp.argmax
        if (inter * bu > bi * ua) { bi = inter; bu = ua; bestm = m; }
    }

    const bool positive = (2.0f * bi >= bu);   // iou >= 0.5
    float local = 0.0f;
    if (positive) {
        const float clsv = s_meta[bestm].y;
        int ac = (int)fminf(fmaxf(clsv, 0.0f), (float)(NCLS - 1));
        const float* prow = pred + ((size_t)b * NANCH + n) * ROWLEN + 5;
        // BCE vs one-hot: -log(p[ac]) - sum_{c!=ac} log(1-p[c])
        //              = -log(p[ac]) + log(1-p[ac]) - S,  S = sum_c log(1-p[c])
        float S = 0.0f;
        #pragma unroll 8
        for (int c = 0; c < NCLS; ++c)
            S += __logf(1.0f - prow[c]);
        const float pa = prow[ac];
        local = -__logf(pa) + __logf(1.0f - pa) - S;
    }

    // Block reduction (deterministic): wave shuffle then cross-wave via LDS
    float v = local;
    int   c = positive ? 1 : 0;
    #pragma unroll
    for (int off = 32; off > 0; off >>= 1) {
        v += __shfl_down(v, off, 64);
        c += __shfl_down(c, off, 64);
    }
    __shared__ float s_sum[BLK / 64];
    __shared__ int   s_cnt[BLK / 64];
    const int wave = threadIdx.x >> 6;
    if ((threadIdx.x & 63) == 0) { s_sum[wave] = v; s_cnt[wave] = c; }
    __syncthreads();
    if (threadIdx.x == 0) {
        float t = 0.0f; int tc = 0;
        #pragma unroll
        for (int w = 0; w < BLK / 64; ++w) { t += s_sum[w]; tc += s_cnt[w]; }
        psum[b * BLKS_PER_IMG + blk] = t;
        pcnt[b * BLKS_PER_IMG + blk] = tc;
    }
}

// Kernel 2: reduce 48 partials per image -> final losses; write all outputs.
__global__ __launch_bounds__(64) void yolo_finalize(
    const float* __restrict__ psum,
    const int*   __restrict__ pcnt,
    float* __restrict__ out)             // (2, B): [cls_losses; reg_losses=0]
{
    const int b = blockIdx.x;
    const int t = threadIdx.x;           // 64 threads
    float v = (t < BLKS_PER_IMG) ? psum[b * BLKS_PER_IMG + t] : 0.0f;
    int   c = (t < BLKS_PER_IMG) ? pcnt[b * BLKS_PER_IMG + t] : 0;
    #pragma unroll
    for (int off = 32; off > 0; off >>= 1) {
        v += __shfl_down(v, off, 64);
        c += __shfl_down(c, off, 64);
    }
    if (t == 0) {
        const int np = (c > 1) ? c : 1;
        out[b]         = v / (float)np;  // cls_loss
        out[BATCH + b] = 0.0f;           // reg_loss (no-op branch in source)
    }
}

extern "C" void kernel_launch(void* const* d_in, const int* in_sizes, int n_in,
                              void* d_out, int out_size, void* d_ws, size_t ws_size,
                              hipStream_t stream) {
    const float* pred    = (const float*)d_in[0];   // (B, A, G, G, 85)
    const float* ann     = (const float*)d_in[1];   // (B, MAXB, 5)
    const float* anchors = (const float*)d_in[2];   // (A, G, G, 4)
    float* out = (float*)d_out;

    float* psum = (float*)d_ws;
    int*   pcnt = (int*)((char*)d_ws + sizeof(float) * BATCH * BLKS_PER_IMG);

    dim3 grid1(BLKS_PER_IMG, BATCH);
    yolo_match_bce<<<grid1, BLK, 0, stream>>>(pred, ann, anchors, psum, pcnt);
    yolo_finalize<<<BATCH, 64, 0, stream>>>(psum, pcnt, out);
}